// Round 10
// baseline (197.747 us; speedup 1.0000x reference)
//
#include <hip/hip_runtime.h>
#include <cstddef>
#include <cstdint>

#define IN_F 512
#define OUT_F 128
#define NREL 10
#define MAXBINS 16000
#define CCHUNK 32768

typedef __attribute__((ext_vector_type(8))) short short8;
typedef __attribute__((ext_vector_type(4))) float f32x4;
typedef __bf16 bf16x2 __attribute__((ext_vector_type(2)));
typedef float f32x2 __attribute__((ext_vector_type(2)));

static const int kNSrc[NREL]   = {8000,16000,8000,16000,8000,4000,8000,4000,16000,4000};
static const int kNDst[NREL]   = {8000,16000,16000,8000,4000,8000,4000,8000,4000,16000};
static const int kNEdges[NREL] = {200000,800000,400000,400000,100000,100000,100000,100000,150000,150000};
static const int kRelSrcType[NREL] = {0,1,0,1,0,2,0,3,1,2};
static const int kNNodes[4] = {8000,16000,4000,4000};
static const size_t kOutOff[4] = {0, 8000ull*OUT_F, 24000ull*OUT_F, 28000ull*OUT_F};
static const size_t kHbOff[4] = {0, 8000ull*IN_F, 24000ull*IN_F, 28000ull*IN_F};
static const int kDstRels[4][4] = {{0,3,5,7},{1,2,9,-1},{4,8,-1,-1},{6,-1,-1,-1}};
static const int kNDstRels[4] = {4,3,2,1};

// chunk tables (CCHUNK=32768): nblk = {7,25,13,13,4,4,4,4,5,5}, sum 84
__device__ const int kCntCum[21] = {0,7,32,45,58,62,66,70,74,79,84,
                                    91,116,129,142,146,150,154,158,163,168};
__device__ const int kCvtCum[5]  = {0,32,95,111,127};   // 16384-vec8 chunks
__device__ const int kPlcCum[11] = {0,7,32,45,58,62,66,70,74,79,84};
#define N_CNT_CH 168
#define N_CVT_CH 127
#define PREP_BLOCKS (N_CNT_CH + N_CVT_CH + NREL)   // 305

__device__ __forceinline__ unsigned short f2bf(float f) {
  union { float f; unsigned u; } v; v.f = f;
  unsigned r = v.u + 0x7fffu + ((v.u >> 16) & 1u);
  return (unsigned short)(r >> 16);
}
// packed bf16-pair -> f32-pair accumulate
__device__ __forceinline__ void acc8(f32x2* a, uint4 u) {
  union { unsigned v; bf16x2 h; } c0, c1, c2, c3;
  c0.v = u.x; c1.v = u.y; c2.v = u.z; c3.v = u.w;
  a[0] += __builtin_convertvector(c0.h, f32x2);
  a[1] += __builtin_convertvector(c1.h, f32x2);
  a[2] += __builtin_convertvector(c2.h, f32x2);
  a[3] += __builtin_convertvector(c3.h, f32x2);
}
// async global->LDS, 16B/lane; LDS dest = uniform base + lane*16 (m97 pattern)
__device__ __forceinline__ void gl_lds16(const unsigned short* g, unsigned short* l) {
  __builtin_amdgcn_global_load_lds(
      (const __attribute__((address_space(1))) unsigned int*)(g),
      (__attribute__((address_space(3))) unsigned int*)(l), 16, 0, 0);
}

// ---------------- fused prep: flat chunks — count(0..167) | cvt(168..294) | WT(295..304)
struct CountJob { const int* idx; unsigned short* H; int n_edges; int nbins; };
struct PrepParams {
  CountJob cj[2 * NREL];
  const float* csrc[4]; unsigned short* cdst[4]; int cn8[4];
  const float* W[NREL]; unsigned short* WT[NREL];
};

__global__ __launch_bounds__(1024) void k_prep(PrepParams p) {
  __shared__ int lb[MAXBINS];
  const int c = blockIdx.x;
  const int t = threadIdx.x;
  if (c < N_CNT_CH) {
    int j = 0;
    while (c >= kCntCum[j + 1]) ++j;
    const CountJob J = p.cj[j];
    const int e0 = (c - kCntCum[j]) * CCHUNK;
    const int eend = (e0 + CCHUNK < J.n_edges) ? e0 + CCHUNK : J.n_edges;
    for (int d = t; d < J.nbins; d += 1024) lb[d] = 0;
    __syncthreads();
    for (int e = e0 + t * 4; e < eend; e += 4096) {   // int4: 4 edges in flight/thread
      const int4 v = *(const int4*)(J.idx + e);
      atomicAdd(&lb[v.x], 1); atomicAdd(&lb[v.y], 1);
      atomicAdd(&lb[v.z], 1); atomicAdd(&lb[v.w], 1);
    }
    __syncthreads();
    unsigned short* Hrow = J.H + (size_t)(c - kCntCum[j]) * J.nbins;
    for (int d = t; d < J.nbins; d += 1024) Hrow[d] = (unsigned short)lb[d];
  } else if (c < N_CNT_CH + N_CVT_CH) {
    const int u = c - N_CNT_CH;
    int ty = 0;
    while (u >= kCvtCum[ty + 1]) ++ty;
    const int i0 = (u - kCvtCum[ty]) * 16384;
    const int n8 = p.cn8[ty];
    const int i1 = (i0 + 16384 < n8) ? i0 + 16384 : n8;
    const float* src = p.csrc[ty];
    unsigned short* dst = p.cdst[ty];
    for (int i = i0 + t; i < i1; i += 1024) {
      const float4 v0 = *(const float4*)(src + (size_t)i * 8);
      const float4 v1 = *(const float4*)(src + (size_t)i * 8 + 4);
      uint4 o;
      o.x = (unsigned)f2bf(v0.x) | ((unsigned)f2bf(v0.y) << 16);
      o.y = (unsigned)f2bf(v0.z) | ((unsigned)f2bf(v0.w) << 16);
      o.z = (unsigned)f2bf(v1.x) | ((unsigned)f2bf(v1.y) << 16);
      o.w = (unsigned)f2bf(v1.z) | ((unsigned)f2bf(v1.w) << 16);
      *(uint4*)(dst + (size_t)i * 8) = o;
    }
  } else {
    const int r = c - N_CNT_CH - N_CVT_CH;
    const float* W = p.W[r];
    unsigned short* WT = p.WT[r];
    for (int g = t; g < IN_F * OUT_F / 4; g += 1024) {
      const int k = g >> 5;
      const int n0 = (g & 31) * 4;
      const float4 w = *(const float4*)(W + (size_t)k * OUT_F + n0);
      WT[(size_t)(n0 + 0) * IN_F + k] = f2bf(w.x);
      WT[(size_t)(n0 + 1) * IN_F + k] = f2bf(w.y);
      WT[(size_t)(n0 + 2) * IN_F + k] = f2bf(w.z);
      WT[(size_t)(n0 + 3) * IN_F + k] = f2bf(w.w);
    }
  }
}

// ---------------- fused column-sum + per-bin prefix over H (one pass) ----------------
struct SBJob { unsigned short* H; int* tot; int nbins; int nblocks; int prefix; };
struct SBParams { SBJob j[2 * NREL]; };

__global__ __launch_bounds__(256) void k_sumbase(SBParams p) {
  SBJob J = p.j[blockIdx.y];
  const int bin = blockIdx.x * 256 + threadIdx.x;
  if (bin >= J.nbins) return;
  int run = 0;
  if (J.prefix) {
    for (int b = 0; b < J.nblocks; ++b) {
      const size_t o = (size_t)b * J.nbins + bin;
      const int cc = J.H[o];
      J.H[o] = (unsigned short)run;
      run += cc;
    }
  } else {
    for (int b = 0; b < J.nblocks; ++b) run += J.H[(size_t)b * J.nbins + bin];
  }
  J.tot[bin] = run;
}

// ---------------- exclusive scan (one 512-thread block per relation, n<=16384) -------
struct ScanRel { const int* tot; int* rowstart; int n; };
struct ScanParams { ScanRel r[NREL]; };

__global__ __launch_bounds__(512) void k_scan(ScanParams p) {
  ScanRel R = p.r[blockIdx.x];
  const int t = threadIdx.x;
  const int lane = t & 63, wv = t >> 6;
  const int base = t * 32;
  int v[32];
  int s = 0;
#pragma unroll
  for (int i = 0; i < 32; ++i) {
    int e = base + i;
    int x = (e < R.n) ? R.tot[e] : 0;
    v[i] = s; s += x;
  }
  int inc = s;
#pragma unroll
  for (int off = 1; off < 64; off <<= 1) {
    int u = __shfl_up(inc, off);
    if (lane >= off) inc += u;
  }
  __shared__ int wsum[8];
  if (lane == 63) wsum[wv] = inc;
  __syncthreads();
  int carry = 0, total = 0;
#pragma unroll
  for (int w = 0; w < 8; ++w) {
    int x = wsum[w];
    if (w < wv) carry += x;
    total += x;
  }
  const int tb = carry + (inc - s);
#pragma unroll
  for (int i = 0; i < 32; ++i) {
    int e = base + i;
    if (e < R.n) R.rowstart[e] = tb + v[i];
  }
  if (t == 0) R.rowstart[R.n] = total;
}

// ---------------- place edges via LDS cursors (flat 84 chunks, int4 loads) -----------
struct PlaceJob { const int* src; const int* dst; const unsigned short* Hpre; const int* rowstart;
                  unsigned short* csr; int n_edges; int nbins; };
struct PlaceParams { PlaceJob j[NREL]; };

__global__ __launch_bounds__(1024) void k_place(PlaceParams p) {
  __shared__ int lb[MAXBINS];
  const int c = blockIdx.x;
  int j = 0;
  while (c >= kPlcCum[j + 1]) ++j;
  const PlaceJob J = p.j[j];
  const int ch = c - kPlcCum[j];
  const int e0 = ch * CCHUNK;
  const int eend = (e0 + CCHUNK < J.n_edges) ? e0 + CCHUNK : J.n_edges;
  const int t = threadIdx.x;
  const unsigned short* Hrow = J.Hpre + (size_t)ch * J.nbins;
  for (int d = t; d < J.nbins; d += 1024) lb[d] = J.rowstart[d] + (int)Hrow[d];
  __syncthreads();
  for (int e = e0 + t * 4; e < eend; e += 4096) {
    const int4 dv = *(const int4*)(J.dst + e);
    const int4 sv = *(const int4*)(J.src + e);
    const int p0 = atomicAdd(&lb[dv.x], 1); J.csr[p0] = (unsigned short)sv.x;
    const int p1 = atomicAdd(&lb[dv.y], 1); J.csr[p1] = (unsigned short)sv.y;
    const int p2 = atomicAdd(&lb[dv.z], 1); J.csr[p2] = (unsigned short)sv.z;
    const int p3 = atomicAdd(&lb[dv.w], 1); J.csr[p3] = (unsigned short)sv.w;
  }
}

// ---------------- y_r = (hb @ W_r) * deg_out^-1/2 — m97-style gload_lds MFMA ---------
struct GemmRel { const unsigned short* hb; const unsigned short* WT; unsigned short* y;
                 const int* deg_out; int n_src; };
struct GemmParams { GemmRel r[NREL]; };

#define GEMM_JOBS 723

__global__ __launch_bounds__(256) void k_gemm(GemmParams p) {
  // bijective XCD swizzle: orig -> jobid (m204)
  const int orig = blockIdx.x;
  const int xcd = orig & 7;
  const int i8 = orig >> 3;
  const int q = GEMM_JOBS / 8, rm = GEMM_JOBS % 8;   // 90, 3
  const int g = (xcd < rm ? xcd * (q + 1) : rm * (q + 1) + (xcd - rm) * q) + i8;
  static const int dr[4] = {0, 2, 4, 6};
  static const int pr[3] = {1, 3, 8};
  static const int xr[2] = {5, 9};
  int rel, tile;
  if (g < 252)      { rel = dr[g & 3]; tile = g >> 2; }
  else if (g < 627) { int u = g - 252; rel = pr[u % 3]; tile = u / 3; }
  else if (g < 691) { int u = g - 627; rel = xr[u & 1]; tile = u >> 1; }
  else              { rel = 7; tile = g - 691; }

  const GemmRel R = p.r[rel];
  const int m0 = tile * 128;

  __shared__ unsigned short As[128 * 64];   // [row][64 shorts], slots XOR-swizzled
  __shared__ unsigned short Bs[128 * 64];

  const int t = threadIdx.x;
  const int lane = t & 63, wid = t >> 6;
  const int wm = (wid >> 1) * 64, wn = (wid & 1) * 64;
  const int l16 = lane & 15;
  const int fcol = lane >> 4;
  const int srow8 = lane >> 3;
  const int slot  = lane & 7;
  const int scol  = (slot ^ srow8) * 8;

  const unsigned short* ga[4];
  const unsigned short* gb[4];
#pragma unroll
  for (int i = 0; i < 4; ++i) {
    const int lrow = wid * 32 + i * 8 + srow8;
    int grow = m0 + lrow;
    if (grow > R.n_src - 1) grow = R.n_src - 1;
    ga[i] = R.hb + (size_t)grow * IN_F + scol;
    gb[i] = R.WT + (size_t)lrow * IN_F + scol;
  }

  f32x4 acc[4][4];
#pragma unroll
  for (int i = 0; i < 4; ++i)
#pragma unroll
    for (int j = 0; j < 4; ++j) acc[i][j] = (f32x4){0.f, 0.f, 0.f, 0.f};

#pragma unroll 1
  for (int s = 0; s < 8; ++s) {
    const int k0 = s * 64;
#pragma unroll
    for (int i = 0; i < 4; ++i) {
      gl_lds16(ga[i] + k0, &As[(wid * 32 + i * 8) * 64]);
      gl_lds16(gb[i] + k0, &Bs[(wid * 32 + i * 8) * 64]);
    }
    __syncthreads();
#pragma unroll
    for (int kk = 0; kk < 2; ++kk) {
      const int csl = ((kk * 4 + fcol) ^ (l16 & 7)) * 8;
      short8 af[4], bf[4];
#pragma unroll
      for (int f = 0; f < 4; ++f) {
        af[f] = *(const short8*)&As[(wm + f * 16 + l16) * 64 + csl];
        bf[f] = *(const short8*)&Bs[(wn + f * 16 + l16) * 64 + csl];
      }
#pragma unroll
      for (int i = 0; i < 4; ++i)
#pragma unroll
        for (int j = 0; j < 4; ++j)
          acc[i][j] = __builtin_amdgcn_mfma_f32_16x16x32_bf16(af[i], bf[j], acc[i][j], 0, 0, 0);
    }
    __syncthreads();
  }

  const int r4 = (lane >> 4) * 4;  // C/D: col=lane&15, row=(lane>>4)*4+q
#pragma unroll
  for (int i = 0; i < 4; ++i) {
#pragma unroll
    for (int qq = 0; qq < 4; ++qq) {
      const int row = m0 + wm + i * 16 + r4 + qq;
      if (row < R.n_src) {
        const int d = R.deg_out[row];
        const float sc = rsqrtf((float)(d > 1 ? d : 1));
#pragma unroll
        for (int j = 0; j < 4; ++j) {
          const int col = wn + j * 16 + l16;
          R.y[(size_t)row * OUT_F + col] = f2bf(acc[i][j][qq] * sc);
        }
      }
    }
  }
}

// ---------------- gather-aggregate + bias + relu (one wave per node, 16 lanes/row) ---
struct AggRel { const int* rowstart; const unsigned short* csr; const unsigned short* y; const float* b; };
struct AggType { AggRel r[4]; int n_rels; int n_nodes; float* out; };
struct AggParams { AggType t[4]; };

__global__ __launch_bounds__(256) void k_aggregate(AggParams p) {
  const AggType& T = p.t[blockIdx.y];
  const int node = blockIdx.x * 4 + (threadIdx.x >> 6);
  if (node >= T.n_nodes) return;
  const int lane = threadIdx.x & 63;
  const int quarter = lane >> 4;
  const int c8 = (lane & 15) * 8;
  f32x2 ac2[4] = {{0.f,0.f},{0.f,0.f},{0.f,0.f},{0.f,0.f}};
  float bs[8] = {0,0,0,0,0,0,0,0};
#pragma unroll
  for (int rr = 0; rr < 4; ++rr) {
    if (rr < T.n_rels) {
      const AggRel R = T.r[rr];
      const int lo = R.rowstart[node];
      const int hi = R.rowstart[node + 1];
      f32x2 rx2[4] = {{0.f,0.f},{0.f,0.f},{0.f,0.f},{0.f,0.f}};
      int k = lo + quarter;
      for (; k + 12 < hi; k += 16) {
        const int s0 = R.csr[k];
        const int s1 = R.csr[k + 4];
        const int s2 = R.csr[k + 8];
        const int s3 = R.csr[k + 12];
        const uint4 u0 = *(const uint4*)(R.y + (size_t)s0 * OUT_F + c8);
        const uint4 u1 = *(const uint4*)(R.y + (size_t)s1 * OUT_F + c8);
        const uint4 u2 = *(const uint4*)(R.y + (size_t)s2 * OUT_F + c8);
        const uint4 u3 = *(const uint4*)(R.y + (size_t)s3 * OUT_F + c8);
        acc8(rx2, u0); acc8(rx2, u1); acc8(rx2, u2); acc8(rx2, u3);
      }
      for (; k < hi; k += 4) {
        const int s0 = R.csr[k];
        const uint4 u0 = *(const uint4*)(R.y + (size_t)s0 * OUT_F + c8);
        acc8(rx2, u0);
      }
      const int deg = hi - lo;
      const float s = rsqrtf((float)(deg > 1 ? deg : 1));
      const f32x2 sc2 = {s, s};
#pragma unroll
      for (int i = 0; i < 4; ++i) ac2[i] += rx2[i] * sc2;
      const float4 b0 = *(const float4*)(R.b + c8);
      const float4 b1 = *(const float4*)(R.b + c8 + 4);
      bs[0] += b0.x; bs[1] += b0.y; bs[2] += b0.z; bs[3] += b0.w;
      bs[4] += b1.x; bs[5] += b1.y; bs[6] += b1.z; bs[7] += b1.w;
    }
  }
  float ac[8] = {ac2[0].x, ac2[0].y, ac2[1].x, ac2[1].y,
                 ac2[2].x, ac2[2].y, ac2[3].x, ac2[3].y};
#pragma unroll
  for (int i = 0; i < 8; ++i) {
    ac[i] += __shfl_xor(ac[i], 16);
    ac[i] += __shfl_xor(ac[i], 32);
    ac[i] += bs[i];
    ac[i] = ac[i] > 0.f ? ac[i] : 0.f;
  }
  if (quarter == 0) {
    float* dst = T.out + (size_t)node * OUT_F + c8;
    float4 o0 = {ac[0], ac[1], ac[2], ac[3]};
    float4 o1 = {ac[4], ac[5], ac[6], ac[7]};
    *(float4*)dst = o0;
    *(float4*)(dst + 4) = o1;
  }
}

// ---------------- host ----------------
extern "C" void kernel_launch(void* const* d_in, const int* in_sizes, int n_in,
                              void* d_out, int out_size, void* d_ws, size_t ws_size,
                              hipStream_t stream) {
  const float* h[4];
  for (int i = 0; i < 4; ++i) h[i] = (const float*)d_in[i];
  const float* W[NREL]; const float* b[NREL];
  const int* src[NREL]; const int* dst[NREL];
  for (int r = 0; r < NREL; ++r) {
    W[r]   = (const float*)d_in[4 + 2 * r];
    b[r]   = (const float*)d_in[5 + 2 * r];
    src[r] = (const int*)d_in[24 + 2 * r];
    dst[r] = (const int*)d_in[25 + 2 * r];
  }
  float* out = (float*)d_out;

  int nblk[NREL];
  for (int r = 0; r < NREL; ++r) nblk[r] = (kNEdges[r] + CCHUNK - 1) / CCHUNK;

  char* ws = (char*)d_ws;
  size_t off = 0;
  auto alloc = [&](size_t bytes) -> char* {
    char* p = ws + off;
    off = (off + bytes + 255) & ~(size_t)255;
    return p;
  };
  int* degO[NREL];
  { char* base = alloc((size_t)92000 * 4); size_t o = 0;
    for (int r = 0; r < NREL; ++r) { degO[r] = (int*)(base + o); o += (size_t)kNSrc[r] * 4; } }
  int* totI[NREL];
  { char* base = alloc((size_t)92000 * 4); size_t o = 0;
    for (int r = 0; r < NREL; ++r) { totI[r] = (int*)(base + o); o += (size_t)kNDst[r] * 4; } }
  int* rowst[NREL];
  { char* base = alloc((size_t)(92000 + NREL) * 4); size_t o = 0;
    for (int r = 0; r < NREL; ++r) { rowst[r] = (int*)(base + o); o += (size_t)(kNDst[r] + 1) * 4; } }
  unsigned short* csr[NREL];
  { char* base = alloc((size_t)2500000 * 2); size_t o = 0;
    for (int r = 0; r < NREL; ++r) { csr[r] = (unsigned short*)(base + o); o += (size_t)kNEdges[r] * 2; } }
  unsigned short* Hsrc[NREL]; unsigned short* Hdst[NREL];
  { size_t tot = 0;
    for (int r = 0; r < NREL; ++r) tot += (size_t)nblk[r] * (kNSrc[r] + kNDst[r]);
    char* base = alloc(tot * 2); size_t o = 0;
    for (int r = 0; r < NREL; ++r) { Hsrc[r] = (unsigned short*)(base + o); o += (size_t)nblk[r] * kNSrc[r] * 2; }
    for (int r = 0; r < NREL; ++r) { Hdst[r] = (unsigned short*)(base + o); o += (size_t)nblk[r] * kNDst[r] * 2; } }
  unsigned short* y[NREL];
  { char* base = alloc((size_t)92000 * OUT_F * 2); size_t o = 0;
    for (int r = 0; r < NREL; ++r) { y[r] = (unsigned short*)(base + o); o += (size_t)kNSrc[r] * OUT_F * 2; } }
  unsigned short* WT[NREL];
  { char* base = alloc((size_t)NREL * IN_F * OUT_F * 2); size_t o = 0;
    for (int r = 0; r < NREL; ++r) { WT[r] = (unsigned short*)(base + o); o += (size_t)IN_F * OUT_F * 2; } }
  unsigned short* hb = (unsigned short*)alloc((size_t)32000 * IN_F * 2);

  // fused prep: histograms + h->bf16 + W^T (flat chunks)
  PrepParams pr;
  for (int r = 0; r < NREL; ++r) {
    pr.cj[r]        = CountJob{src[r], Hsrc[r], kNEdges[r], kNSrc[r]};
    pr.cj[NREL + r] = CountJob{dst[r], Hdst[r], kNEdges[r], kNDst[r]};
  }
  for (int ty = 0; ty < 4; ++ty) {
    pr.csrc[ty] = h[ty];
    pr.cdst[ty] = hb + kHbOff[ty];
    pr.cn8[ty] = kNNodes[ty] * IN_F / 8;
  }
  for (int r = 0; r < NREL; ++r) { pr.W[r] = W[r]; pr.WT[r] = WT[r]; }
  k_prep<<<PREP_BLOCKS, 1024, 0, stream>>>(pr);

  // fused column-sum (src) + prefix (dst)
  SBParams sb;
  for (int r = 0; r < NREL; ++r) {
    sb.j[r]        = SBJob{Hsrc[r], degO[r], kNSrc[r], nblk[r], 0};
    sb.j[NREL + r] = SBJob{Hdst[r], totI[r], kNDst[r], nblk[r], 1};
  }
  k_sumbase<<<dim3((16000 + 255) / 256, 2 * NREL), 256, 0, stream>>>(sb);

  ScanParams sp;
  for (int r = 0; r < NREL; ++r) sp.r[r] = ScanRel{totI[r], rowst[r], kNDst[r]};
  k_scan<<<NREL, 512, 0, stream>>>(sp);

  PlaceParams pp;
  for (int r = 0; r < NREL; ++r)
    pp.j[r] = PlaceJob{src[r], dst[r], Hdst[r], rowst[r], csr[r], kNEdges[r], kNDst[r]};
  k_place<<<84, 1024, 0, stream>>>(pp);

  GemmParams gp;
  for (int r = 0; r < NREL; ++r)
    gp.r[r] = GemmRel{hb + kHbOff[kRelSrcType[r]], WT[r], y[r], degO[r], kNSrc[r]};
  k_gemm<<<GEMM_JOBS, 256, 0, stream>>>(gp);

  AggParams ap;
  for (int ti = 0; ti < 4; ++ti) {
    AggType& T = ap.t[ti];
    T.n_nodes = kNNodes[ti];
    T.n_rels = kNDstRels[ti];
    T.out = out + kOutOff[ti];
    for (int j = 0; j < 4; ++j) {
      int r = kDstRels[ti][j];
      if (r < 0) r = kDstRels[ti][0];
      T.r[j] = AggRel{rowst[r], csr[r], y[r], b[r]};
    }
  }
  k_aggregate<<<dim3((16000 + 3) / 4, 4), 256, 0, stream>>>(ap);
}

// Round 11
// 192.383 us; speedup vs baseline: 1.0279x; 1.0279x over previous
//
#include <hip/hip_runtime.h>
#include <cstddef>
#include <cstdint>

#define IN_F 512
#define OUT_F 128
#define NREL 10
#define MAXBINS 16000

typedef __attribute__((ext_vector_type(8))) short short8;
typedef __attribute__((ext_vector_type(4))) float f32x4;
typedef __bf16 bf16x2 __attribute__((ext_vector_type(2)));
typedef float f32x2 __attribute__((ext_vector_type(2)));

static const int kNSrc[NREL]   = {8000,16000,8000,16000,8000,4000,8000,4000,16000,4000};
static const int kNDst[NREL]   = {8000,16000,16000,8000,4000,8000,4000,8000,4000,16000};
static const int kNEdges[NREL] = {200000,800000,400000,400000,100000,100000,100000,100000,150000,150000};
static const int kRelSrcType[NREL] = {0,1,0,1,0,2,0,3,1,2};
static const int kNNodes[4] = {8000,16000,4000,4000};
static const size_t kOutOff[4] = {0, 8000ull*OUT_F, 24000ull*OUT_F, 28000ull*OUT_F};
static const size_t kHbOff[4] = {0, 8000ull*IN_F, 24000ull*IN_F, 28000ull*IN_F};
static const int kDstRels[4][4] = {{0,3,5,7},{1,2,9,-1},{4,8,-1,-1},{6,-1,-1,-1}};
static const int kNDstRels[4] = {4,3,2,1};
static const int kNblk8[NREL] = {25,98,49,49,13,13,13,13,19,19};   // ceil(E/8192), sum 311

// count chunks (8192): jobs 0..9 = src, 10..19 = dst, both use kNblk8
__device__ const int kCntCum[21] = {0,25,123,172,221,234,247,260,273,292,311,
                                    336,434,483,532,545,558,571,584,603,622};
#define N_CNT_CH 622
// place chunks (16384 = 2 count-chunks): ceil(E/16384) = {13,49,25,25,7,7,7,7,10,10}
__device__ const int kPlcCum[11] = {0,13,62,87,112,119,126,133,140,150,160};
#define N_PLC_CH 160

__device__ __forceinline__ unsigned short f2bf(float f) {
  union { float f; unsigned u; } v; v.f = f;
  unsigned r = v.u + 0x7fffu + ((v.u >> 16) & 1u);
  return (unsigned short)(r >> 16);
}
// packed bf16-pair -> f32-pair accumulate
__device__ __forceinline__ void acc8(f32x2* a, uint4 u) {
  union { unsigned v; bf16x2 h; } c0, c1, c2, c3;
  c0.v = u.x; c1.v = u.y; c2.v = u.z; c3.v = u.w;
  a[0] += __builtin_convertvector(c0.h, f32x2);
  a[1] += __builtin_convertvector(c1.h, f32x2);
  a[2] += __builtin_convertvector(c2.h, f32x2);
  a[3] += __builtin_convertvector(c3.h, f32x2);
}
// async global->LDS, 16B/lane; LDS dest = uniform base + lane*16 (m97 pattern)
__device__ __forceinline__ void gl_lds16(const unsigned short* g, unsigned short* l) {
  __builtin_amdgcn_global_load_lds(
      (const __attribute__((address_space(1))) unsigned int*)(g),
      (__attribute__((address_space(3))) unsigned int*)(l), 16, 0, 0);
}

// ---------------- streaming cvt (h->bf16) + W^T, zero LDS, full occupancy ------------
struct CvtParams { const float* csrc[4]; unsigned short* cdst[4]; int cn8[4];
                   const float* W[NREL]; unsigned short* WT[NREL]; };

__global__ __launch_bounds__(256) void k_cvtwt(CvtParams p) {
  const int yj = blockIdx.y;
  const int t = threadIdx.x;
  const int stride = gridDim.x * 256;
  if (yj < 4) {
    const int n8 = p.cn8[yj];
    const float* src = p.csrc[yj];
    unsigned short* dst = p.cdst[yj];
    for (int i = blockIdx.x * 256 + t; i < n8; i += stride) {
      const float4 v0 = *(const float4*)(src + (size_t)i * 8);
      const float4 v1 = *(const float4*)(src + (size_t)i * 8 + 4);
      uint4 o;
      o.x = (unsigned)f2bf(v0.x) | ((unsigned)f2bf(v0.y) << 16);
      o.y = (unsigned)f2bf(v0.z) | ((unsigned)f2bf(v0.w) << 16);
      o.z = (unsigned)f2bf(v1.x) | ((unsigned)f2bf(v1.y) << 16);
      o.w = (unsigned)f2bf(v1.z) | ((unsigned)f2bf(v1.w) << 16);
      *(uint4*)(dst + (size_t)i * 8) = o;
    }
  } else {
    const int r = yj - 4;
    const float* W = p.W[r];
    unsigned short* WT = p.WT[r];
    for (int g = blockIdx.x * 256 + t; g < IN_F * OUT_F / 4; g += stride) {
      const int k = g >> 5;
      const int n0 = (g & 31) * 4;
      const float4 w = *(const float4*)(W + (size_t)k * OUT_F + n0);
      WT[(size_t)(n0 + 0) * IN_F + k] = f2bf(w.x);
      WT[(size_t)(n0 + 1) * IN_F + k] = f2bf(w.y);
      WT[(size_t)(n0 + 2) * IN_F + k] = f2bf(w.z);
      WT[(size_t)(n0 + 3) * IN_F + k] = f2bf(w.w);
    }
  }
}

// ---------------- count: 8192-edge chunks, packed u16 LDS counters (32KB) ------------
struct CountJob { const int* idx; unsigned short* H; int n_edges; int nbins; };
struct CountParams { CountJob cj[2 * NREL]; };

__global__ __launch_bounds__(512) void k_count(CountParams p) {
  __shared__ unsigned lb[MAXBINS / 2];   // 2 bins per word; chunk<=8192 so no overflow
  const int c = blockIdx.x;
  const int t = threadIdx.x;
  int j = 0;
  while (c >= kCntCum[j + 1]) ++j;
  const CountJob J = p.cj[j];
  const int ch = c - kCntCum[j];
  const int e0 = ch * 8192;
  const int eend = (e0 + 8192 < J.n_edges) ? e0 + 8192 : J.n_edges;
  const int nw = J.nbins >> 1;
  for (int d = t; d < nw; d += 512) lb[d] = 0;
  __syncthreads();
  for (int e = e0 + t * 4; e < eend; e += 2048) {
    const int4 v = *(const int4*)(J.idx + e);
    atomicAdd(&lb[v.x >> 1], 1u << ((v.x & 1) << 4));
    atomicAdd(&lb[v.y >> 1], 1u << ((v.y & 1) << 4));
    atomicAdd(&lb[v.z >> 1], 1u << ((v.z & 1) << 4));
    atomicAdd(&lb[v.w >> 1], 1u << ((v.w & 1) << 4));
  }
  __syncthreads();
  unsigned short* Hrow = J.H + (size_t)ch * J.nbins;
  for (int d = t; d < nw; d += 512) *(unsigned*)&Hrow[d * 2] = lb[d];  // u16 pair
}

// ---------------- fused column-sum (src) + per-bin prefix (dst) over H ---------------
struct SBJob { unsigned short* H; int* tot; int nbins; int nblocks; int prefix; };
struct SBParams { SBJob j[2 * NREL]; };

__global__ __launch_bounds__(256) void k_sumbase(SBParams p) {
  SBJob J = p.j[blockIdx.y];
  const int bin = blockIdx.x * 256 + threadIdx.x;
  if (bin >= J.nbins) return;
  int run = 0;
  if (J.prefix) {
    for (int b = 0; b < J.nblocks; ++b) {
      const size_t o = (size_t)b * J.nbins + bin;
      const int cc = J.H[o];
      J.H[o] = (unsigned short)run;
      run += cc;
    }
  } else {
    for (int b = 0; b < J.nblocks; ++b) run += J.H[(size_t)b * J.nbins + bin];
  }
  J.tot[bin] = run;
}

// ---------------- exclusive scan (one 512-thread block per relation, n<=16384) -------
struct ScanRel { const int* tot; int* rowstart; int n; };
struct ScanParams { ScanRel r[NREL]; };

__global__ __launch_bounds__(512) void k_scan(ScanParams p) {
  ScanRel R = p.r[blockIdx.x];
  const int t = threadIdx.x;
  const int lane = t & 63, wv = t >> 6;
  const int base = t * 32;
  int v[32];
  int s = 0;
#pragma unroll
  for (int i = 0; i < 32; ++i) {
    int e = base + i;
    int x = (e < R.n) ? R.tot[e] : 0;
    v[i] = s; s += x;
  }
  int inc = s;
#pragma unroll
  for (int off = 1; off < 64; off <<= 1) {
    int u = __shfl_up(inc, off);
    if (lane >= off) inc += u;
  }
  __shared__ int wsum[8];
  if (lane == 63) wsum[wv] = inc;
  __syncthreads();
  int carry = 0, total = 0;
#pragma unroll
  for (int w = 0; w < 8; ++w) {
    int x = wsum[w];
    if (w < wv) carry += x;
    total += x;
  }
  const int tb = carry + (inc - s);
#pragma unroll
  for (int i = 0; i < 32; ++i) {
    int e = base + i;
    if (e < R.n) R.rowstart[e] = tb + v[i];
  }
  if (t == 0) R.rowstart[R.n] = total;
}

// ---------------- place: 16384-edge chunks (= 2 count-chunks), LDS cursors -----------
struct PlaceJob { const int* src; const int* dst; const unsigned short* Hpre; const int* rowstart;
                  unsigned short* csr; int n_edges; int nbins; };
struct PlaceParams { PlaceJob j[NREL]; };

__global__ __launch_bounds__(1024) void k_place(PlaceParams p) {
  __shared__ int lb[MAXBINS];
  const int c = blockIdx.x;
  const int t = threadIdx.x;
  int j = 0;
  while (c >= kPlcCum[j + 1]) ++j;
  const PlaceJob J = p.j[j];
  const int ch = c - kPlcCum[j];
  const int e0 = ch * 16384;
  const int eend = (e0 + 16384 < J.n_edges) ? e0 + 16384 : J.n_edges;
  // base cursor = rowstart + prefix at count-chunk 2*ch (pair range is contiguous)
  const unsigned short* Hrow = J.Hpre + (size_t)(ch * 2) * J.nbins;
  for (int d = t; d < J.nbins; d += 1024) lb[d] = J.rowstart[d] + (int)Hrow[d];
  __syncthreads();
  for (int e = e0 + t * 4; e < eend; e += 4096) {
    const int4 dv = *(const int4*)(J.dst + e);
    const int4 sv = *(const int4*)(J.src + e);
    const int p0 = atomicAdd(&lb[dv.x], 1); J.csr[p0] = (unsigned short)sv.x;
    const int p1 = atomicAdd(&lb[dv.y], 1); J.csr[p1] = (unsigned short)sv.y;
    const int p2 = atomicAdd(&lb[dv.z], 1); J.csr[p2] = (unsigned short)sv.z;
    const int p3 = atomicAdd(&lb[dv.w], 1); J.csr[p3] = (unsigned short)sv.w;
  }
}

// ---------------- y_r = (hb @ W_r) * deg_out^-1/2 — m97-style gload_lds MFMA ---------
struct GemmRel { const unsigned short* hb; const unsigned short* WT; unsigned short* y;
                 const int* deg_out; int n_src; };
struct GemmParams { GemmRel r[NREL]; };

#define GEMM_JOBS 723

__global__ __launch_bounds__(256) void k_gemm(GemmParams p) {
  // bijective XCD swizzle: orig -> jobid (m204)
  const int orig = blockIdx.x;
  const int xcd = orig & 7;
  const int i8 = orig >> 3;
  const int q = GEMM_JOBS / 8, rm = GEMM_JOBS % 8;   // 90, 3
  const int g = (xcd < rm ? xcd * (q + 1) : rm * (q + 1) + (xcd - rm) * q) + i8;
  static const int dr[4] = {0, 2, 4, 6};
  static const int pr[3] = {1, 3, 8};
  static const int xr[2] = {5, 9};
  int rel, tile;
  if (g < 252)      { rel = dr[g & 3]; tile = g >> 2; }
  else if (g < 627) { int u = g - 252; rel = pr[u % 3]; tile = u / 3; }
  else if (g < 691) { int u = g - 627; rel = xr[u & 1]; tile = u >> 1; }
  else              { rel = 7; tile = g - 691; }

  const GemmRel R = p.r[rel];
  const int m0 = tile * 128;

  __shared__ unsigned short As[128 * 64];   // [row][64 shorts], slots XOR-swizzled
  __shared__ unsigned short Bs[128 * 64];

  const int t = threadIdx.x;
  const int lane = t & 63, wid = t >> 6;
  const int wm = (wid >> 1) * 64, wn = (wid & 1) * 64;
  const int l16 = lane & 15;
  const int fcol = lane >> 4;
  const int srow8 = lane >> 3;
  const int slot  = lane & 7;
  const int scol  = (slot ^ srow8) * 8;

  const unsigned short* ga[4];
  const unsigned short* gb[4];
#pragma unroll
  for (int i = 0; i < 4; ++i) {
    const int lrow = wid * 32 + i * 8 + srow8;
    int grow = m0 + lrow;
    if (grow > R.n_src - 1) grow = R.n_src - 1;
    ga[i] = R.hb + (size_t)grow * IN_F + scol;
    gb[i] = R.WT + (size_t)lrow * IN_F + scol;
  }

  f32x4 acc[4][4];
#pragma unroll
  for (int i = 0; i < 4; ++i)
#pragma unroll
    for (int j = 0; j < 4; ++j) acc[i][j] = (f32x4){0.f, 0.f, 0.f, 0.f};

#pragma unroll 1
  for (int s = 0; s < 8; ++s) {
    const int k0 = s * 64;
#pragma unroll
    for (int i = 0; i < 4; ++i) {
      gl_lds16(ga[i] + k0, &As[(wid * 32 + i * 8) * 64]);
      gl_lds16(gb[i] + k0, &Bs[(wid * 32 + i * 8) * 64]);
    }
    __syncthreads();
#pragma unroll
    for (int kk = 0; kk < 2; ++kk) {
      const int csl = ((kk * 4 + fcol) ^ (l16 & 7)) * 8;
      short8 af[4], bf[4];
#pragma unroll
      for (int f = 0; f < 4; ++f) {
        af[f] = *(const short8*)&As[(wm + f * 16 + l16) * 64 + csl];
        bf[f] = *(const short8*)&Bs[(wn + f * 16 + l16) * 64 + csl];
      }
#pragma unroll
      for (int i = 0; i < 4; ++i)
#pragma unroll
        for (int j = 0; j < 4; ++j)
          acc[i][j] = __builtin_amdgcn_mfma_f32_16x16x32_bf16(af[i], bf[j], acc[i][j], 0, 0, 0);
    }
    __syncthreads();
  }

  const int r4 = (lane >> 4) * 4;  // C/D: col=lane&15, row=(lane>>4)*4+q
#pragma unroll
  for (int i = 0; i < 4; ++i) {
#pragma unroll
    for (int qq = 0; qq < 4; ++qq) {
      const int row = m0 + wm + i * 16 + r4 + qq;
      if (row < R.n_src) {
        const int d = R.deg_out[row];
        const float sc = rsqrtf((float)(d > 1 ? d : 1));
#pragma unroll
        for (int j = 0; j < 4; ++j) {
          const int col = wn + j * 16 + l16;
          R.y[(size_t)row * OUT_F + col] = f2bf(acc[i][j][qq] * sc);
        }
      }
    }
  }
}

// ---------------- gather-aggregate + bias + relu (one wave per node, 16 lanes/row) ---
struct AggRel { const int* rowstart; const unsigned short* csr; const unsigned short* y; const float* b; };
struct AggType { AggRel r[4]; int n_rels; int n_nodes; float* out; };
struct AggParams { AggType t[4]; };

__global__ __launch_bounds__(256) void k_aggregate(AggParams p) {
  const AggType& T = p.t[blockIdx.y];
  const int node = blockIdx.x * 4 + (threadIdx.x >> 6);
  if (node >= T.n_nodes) return;
  const int lane = threadIdx.x & 63;
  const int quarter = lane >> 4;
  const int c8 = (lane & 15) * 8;
  f32x2 ac2[4] = {{0.f,0.f},{0.f,0.f},{0.f,0.f},{0.f,0.f}};
  float bs[8] = {0,0,0,0,0,0,0,0};
#pragma unroll
  for (int rr = 0; rr < 4; ++rr) {
    if (rr < T.n_rels) {
      const AggRel R = T.r[rr];
      const int lo = R.rowstart[node];
      const int hi = R.rowstart[node + 1];
      f32x2 rx2[4] = {{0.f,0.f},{0.f,0.f},{0.f,0.f},{0.f,0.f}};
      int k = lo + quarter;
      for (; k + 12 < hi; k += 16) {
        const int s0 = R.csr[k];
        const int s1 = R.csr[k + 4];
        const int s2 = R.csr[k + 8];
        const int s3 = R.csr[k + 12];
        const uint4 u0 = *(const uint4*)(R.y + (size_t)s0 * OUT_F + c8);
        const uint4 u1 = *(const uint4*)(R.y + (size_t)s1 * OUT_F + c8);
        const uint4 u2 = *(const uint4*)(R.y + (size_t)s2 * OUT_F + c8);
        const uint4 u3 = *(const uint4*)(R.y + (size_t)s3 * OUT_F + c8);
        acc8(rx2, u0); acc8(rx2, u1); acc8(rx2, u2); acc8(rx2, u3);
      }
      for (; k < hi; k += 4) {
        const int s0 = R.csr[k];
        const uint4 u0 = *(const uint4*)(R.y + (size_t)s0 * OUT_F + c8);
        acc8(rx2, u0);
      }
      const int deg = hi - lo;
      const float s = rsqrtf((float)(deg > 1 ? deg : 1));
      const f32x2 sc2 = {s, s};
#pragma unroll
      for (int i = 0; i < 4; ++i) ac2[i] += rx2[i] * sc2;
      const float4 b0 = *(const float4*)(R.b + c8);
      const float4 b1 = *(const float4*)(R.b + c8 + 4);
      bs[0] += b0.x; bs[1] += b0.y; bs[2] += b0.z; bs[3] += b0.w;
      bs[4] += b1.x; bs[5] += b1.y; bs[6] += b1.z; bs[7] += b1.w;
    }
  }
  float ac[8] = {ac2[0].x, ac2[0].y, ac2[1].x, ac2[1].y,
                 ac2[2].x, ac2[2].y, ac2[3].x, ac2[3].y};
#pragma unroll
  for (int i = 0; i < 8; ++i) {
    ac[i] += __shfl_xor(ac[i], 16);
    ac[i] += __shfl_xor(ac[i], 32);
    ac[i] += bs[i];
    ac[i] = ac[i] > 0.f ? ac[i] : 0.f;
  }
  if (quarter == 0) {
    float* dst = T.out + (size_t)node * OUT_F + c8;
    float4 o0 = {ac[0], ac[1], ac[2], ac[3]};
    float4 o1 = {ac[4], ac[5], ac[6], ac[7]};
    *(float4*)dst = o0;
    *(float4*)(dst + 4) = o1;
  }
}

// ---------------- host ----------------
extern "C" void kernel_launch(void* const* d_in, const int* in_sizes, int n_in,
                              void* d_out, int out_size, void* d_ws, size_t ws_size,
                              hipStream_t stream) {
  const float* h[4];
  for (int i = 0; i < 4; ++i) h[i] = (const float*)d_in[i];
  const float* W[NREL]; const float* b[NREL];
  const int* src[NREL]; const int* dst[NREL];
  for (int r = 0; r < NREL; ++r) {
    W[r]   = (const float*)d_in[4 + 2 * r];
    b[r]   = (const float*)d_in[5 + 2 * r];
    src[r] = (const int*)d_in[24 + 2 * r];
    dst[r] = (const int*)d_in[25 + 2 * r];
  }
  float* out = (float*)d_out;

  char* ws = (char*)d_ws;
  size_t off = 0;
  auto alloc = [&](size_t bytes) -> char* {
    char* p = ws + off;
    off = (off + bytes + 255) & ~(size_t)255;
    return p;
  };
  int* degO[NREL];
  { char* base = alloc((size_t)92000 * 4); size_t o = 0;
    for (int r = 0; r < NREL; ++r) { degO[r] = (int*)(base + o); o += (size_t)kNSrc[r] * 4; } }
  int* totI[NREL];
  { char* base = alloc((size_t)92000 * 4); size_t o = 0;
    for (int r = 0; r < NREL; ++r) { totI[r] = (int*)(base + o); o += (size_t)kNDst[r] * 4; } }
  int* rowst[NREL];
  { char* base = alloc((size_t)(92000 + NREL) * 4); size_t o = 0;
    for (int r = 0; r < NREL; ++r) { rowst[r] = (int*)(base + o); o += (size_t)(kNDst[r] + 1) * 4; } }
  unsigned short* csr[NREL];
  { char* base = alloc((size_t)2500000 * 2); size_t o = 0;
    for (int r = 0; r < NREL; ++r) { csr[r] = (unsigned short*)(base + o); o += (size_t)kNEdges[r] * 2; } }
  unsigned short* WT[NREL];
  { char* base = alloc((size_t)NREL * IN_F * OUT_F * 2); size_t o = 0;
    for (int r = 0; r < NREL; ++r) { WT[r] = (unsigned short*)(base + o); o += (size_t)IN_F * OUT_F * 2; } }
  unsigned short* hb = (unsigned short*)alloc((size_t)32000 * IN_F * 2);

  // H region (8192-granular rows) and y overlap: H dead after k_place, y written in k_gemm.
  size_t hBytes = 0;
  for (int r = 0; r < NREL; ++r) hBytes += (size_t)kNblk8[r] * (kNSrc[r] + kNDst[r]) * 2;
  size_t yBytes = (size_t)92000 * OUT_F * 2;
  char* HY = alloc(hBytes > yBytes ? hBytes : yBytes);
  unsigned short* Hsrc[NREL]; unsigned short* Hdst[NREL];
  { size_t o = 0;
    for (int r = 0; r < NREL; ++r) { Hsrc[r] = (unsigned short*)(HY + o); o += (size_t)kNblk8[r] * kNSrc[r] * 2; }
    for (int r = 0; r < NREL; ++r) { Hdst[r] = (unsigned short*)(HY + o); o += (size_t)kNblk8[r] * kNDst[r] * 2; } }
  unsigned short* y[NREL];
  { size_t o = 0;
    for (int r = 0; r < NREL; ++r) { y[r] = (unsigned short*)(HY + o); o += (size_t)kNSrc[r] * OUT_F * 2; } }

  // 1) streaming cvt + W^T (no LDS)
  CvtParams cv;
  for (int ty = 0; ty < 4; ++ty) {
    cv.csrc[ty] = h[ty];
    cv.cdst[ty] = hb + kHbOff[ty];
    cv.cn8[ty] = kNNodes[ty] * IN_F / 8;
  }
  for (int r = 0; r < NREL; ++r) { cv.W[r] = W[r]; cv.WT[r] = WT[r]; }
  k_cvtwt<<<dim3(512, 4 + NREL), 256, 0, stream>>>(cv);

  // 2) count (packed u16 LDS, 8192 chunks)
  CountParams cp;
  for (int r = 0; r < NREL; ++r) {
    cp.cj[r]        = CountJob{src[r], Hsrc[r], kNEdges[r], kNSrc[r]};
    cp.cj[NREL + r] = CountJob{dst[r], Hdst[r], kNEdges[r], kNDst[r]};
  }
  k_count<<<N_CNT_CH, 512, 0, stream>>>(cp);

  // 3) column-sum (src) + prefix (dst)
  SBParams sb;
  for (int r = 0; r < NREL; ++r) {
    sb.j[r]        = SBJob{Hsrc[r], degO[r], kNSrc[r], kNblk8[r], 0};
    sb.j[NREL + r] = SBJob{Hdst[r], totI[r], kNDst[r], kNblk8[r], 1};
  }
  k_sumbase<<<dim3((16000 + 255) / 256, 2 * NREL), 256, 0, stream>>>(sb);

  // 4) per-relation exclusive scan
  ScanParams sp;
  for (int r = 0; r < NREL; ++r) sp.r[r] = ScanRel{totI[r], rowst[r], kNDst[r]};
  k_scan<<<NREL, 512, 0, stream>>>(sp);

  // 5) place
  PlaceParams pp;
  for (int r = 0; r < NREL; ++r)
    pp.j[r] = PlaceJob{src[r], dst[r], Hdst[r], rowst[r], csr[r], kNEdges[r], kNDst[r]};
  k_place<<<N_PLC_CH, 1024, 0, stream>>>(pp);

  // 6) GEMM
  GemmParams gp;
  for (int r = 0; r < NREL; ++r)
    gp.r[r] = GemmRel{hb + kHbOff[kRelSrcType[r]], WT[r], y[r], degO[r], kNSrc[r]};
  k_gemm<<<GEMM_JOBS, 256, 0, stream>>>(gp);

  // 7) aggregate
  AggParams ap;
  for (int ti = 0; ti < 4; ++ti) {
    AggType& T = ap.t[ti];
    T.n_nodes = kNNodes[ti];
    T.n_rels = kNDstRels[ti];
    T.out = out + kOutOff[ti];
    for (int j = 0; j < 4; ++j) {
      int r = kDstRels[ti][j];
      if (r < 0) r = kDstRels[ti][0];
      T.r[j] = AggRel{rowst[r], csr[r], y[r], b[r]};
    }
  }
  k_aggregate<<<dim3((16000 + 3) / 4, 4), 256, 0, stream>>>(ap);
}